// Round 11
// baseline (74.263 us; speedup 1.0000x reference)
//
#include <hip/hip_runtime.h>

// attn_block: GroupNorm(32) -> QKV 1x1 -> full spatial self-attention -> proj -> residual
// B=8, H=W=64 (N=4096 tokens), C=D=64, single head, scale=1/8 (folded into q with log2e).
//
// v11: v10 + k_attn VALU diet: persistent zero-vector MFMA C-operand (no per-tile
//      accumulator zero-init movs) and cvt_pk-friendly bf16 packing (element casts).

typedef __bf16 bf16x8 __attribute__((ext_vector_type(8)));
typedef float f32x16 __attribute__((ext_vector_type(16)));
typedef unsigned u32x2 __attribute__((ext_vector_type(2)));

static __device__ __forceinline__ unsigned short f2b(float f) {
  union { __bf16 b; unsigned short u; } c; c.b = (__bf16)f; return c.u;
}
static __device__ __forceinline__ float b2f(unsigned short u) {
  union { float f; unsigned u; } c; c.u = ((unsigned)u) << 16; return c.f;
}
// A/B-frag (mfma_32x32x16, K-contiguous-8) element offset inside a 64x64 tile.
static __device__ __forceinline__ int a_off(int t, int c) {
  return ((t >> 5) * 4 + (c >> 4)) * 512 + ((t & 31) + 32 * ((c >> 3) & 1)) * 8 + (c & 7);
}
static __device__ __forceinline__ int b_off(int o, int d) {
  return ((o >> 5) * 4 + (d >> 4)) * 512 + ((o & 31) + 32 * ((d >> 3) & 1)) * 8 + (d & 7);
}

#define GLL(src, dst) __builtin_amdgcn_global_load_lds(                        \
    (const __attribute__((address_space(1))) void*)(src),                     \
    (__attribute__((address_space(3))) void*)(dst), 16, 0, 0)

// ---------------- kernel 1: GN partial sums + weight frag conversion -----
__global__ __launch_bounds__(256) void k_part(
    const float* __restrict__ x,
    const float* __restrict__ Wq, const float* __restrict__ Wk,
    const float* __restrict__ Wv, const float* __restrict__ Wp,
    float* __restrict__ part, unsigned short* __restrict__ wsW) {
  const int b = blockIdx.y, ch = blockIdx.x, tid = threadIdx.x;

  if (b == 0) {  // weight conversion: 16384 elems over 32 blocks x 256 thr x 2
    const float* Wsrc[4] = {Wq, Wk, Wv, Wp};
    const int e0 = ch * 512 + tid * 2;
#pragma unroll
    for (int j = 0; j < 2; ++j) {
      const int e = e0 + j, m = e >> 12, idx = e & 4095;
      const int d = idx >> 6, o = idx & 63;
      wsW[m * 4096 + b_off(o, d)] = f2b(Wsrc[m][idx]);
    }
  }

  const size_t base = ((size_t)(b * 4096 + ch * 128)) * 64;
  float s0 = 0.f, q0 = 0.f, s1 = 0.f, q1 = 0.f;
#pragma unroll
  for (int it = 0; it < 8; ++it) {
    const float4 v = *(const float4*)&x[base + (size_t)tid * 4 + (size_t)it * 1024];
    s0 += v.x + v.y; q0 += v.x * v.x + v.y * v.y;
    s1 += v.z + v.w; q1 += v.z * v.z + v.w * v.w;
  }
  for (int m = 16; m < 64; m <<= 1) {
    s0 += __shfl_xor(s0, m); q0 += __shfl_xor(q0, m);
    s1 += __shfl_xor(s1, m); q1 += __shfl_xor(q1, m);
  }
  __shared__ float red[4][16][4];
  const int lane = tid & 63, wv = tid >> 6;
  if (lane < 16) {
    red[wv][lane][0] = s0; red[wv][lane][1] = q0;
    red[wv][lane][2] = s1; red[wv][lane][3] = q1;
  }
  __syncthreads();
  if (tid < 64) {
    const int ci = tid >> 2, sel = tid & 3;
    const float v = red[0][ci][sel] + red[1][ci][sel] +
                    red[2][ci][sel] + red[3][ci][sel];
    const int g = ci * 2 + (sel >> 1);
    part[(((size_t)b * 32 + g) * 32 + ch) * 2 + (sel & 1)] = v;
  }
}

// ---------------- kernel 2: GN stats finalize + GN + QKV proj (MFMA) -----
__global__ __launch_bounds__(256) void k_gnqkv(
    const float* __restrict__ x, const float* __restrict__ gamma,
    const float* __restrict__ beta,
    const float* __restrict__ bq, const float* __restrict__ bk,
    const float* __restrict__ bv,
    const float* __restrict__ part, const unsigned short* __restrict__ wsW,
    unsigned short* __restrict__ qo, unsigned short* __restrict__ ko,
    unsigned short* __restrict__ vo) {
  __shared__ unsigned short hA[4096];  // A-frags of h; reused as V bounce
  __shared__ float2 stl[32];
  const int b = blockIdx.y, tid = threadIdx.x, t0 = blockIdx.x * 64;
  const int w = tid >> 6, lane = tid & 63;
  const int mt = w >> 1, nt = w & 1, hi = lane >> 5;

  bf16x8 wf[3][4];
#pragma unroll
  for (int m = 0; m < 3; ++m)
#pragma unroll
    for (int cc = 0; cc < 4; ++cc)
      wf[m][cc] = *(const bf16x8*)&wsW[m * 4096 + (nt * 4 + cc) * 512 + lane * 8];

  if (tid < 32) {
    const float* p = part + ((size_t)(b * 32 + tid)) * 64;
    float s = 0.f, q = 0.f;
#pragma unroll
    for (int c4 = 0; c4 < 16; ++c4) {
      const float4 v = *(const float4*)&p[c4 * 4];
      s += v.x + v.z; q += v.y + v.w;
    }
    const float mean = s * (1.0f / 8192.0f);
    const float var = fmaxf(q * (1.0f / 8192.0f) - mean * mean, 0.0f);
    stl[tid] = make_float2(mean, rsqrtf(var + 1e-6f));
  }
  __syncthreads();

#pragma unroll
  for (int it = 0; it < 4; ++it) {
    const int idx = tid * 4 + it * 1024;
    const int tl = idx >> 6, c0 = idx & 63;
    const float4 xv = *(const float4*)&x[((size_t)(b * 4096 + t0 + tl)) * 64 + c0];
    const float2 s0 = stl[(c0 >> 1)];
    const float2 s1 = stl[(c0 >> 1) + 1];
    const float4 gm = *(const float4*)&gamma[c0];
    const float4 bt = *(const float4*)&beta[c0];
    ushort4 hv;
    hv.x = f2b((xv.x - s0.x) * s0.y * gm.x + bt.x);
    hv.y = f2b((xv.y - s0.x) * s0.y * gm.y + bt.y);
    hv.z = f2b((xv.z - s1.x) * s1.y * gm.z + bt.z);
    hv.w = f2b((xv.w - s1.x) * s1.y * gm.w + bt.w);
    *(ushort4*)&hA[a_off(tl, c0)] = hv;
  }
  __syncthreads();

  bf16x8 af[4];
#pragma unroll
  for (int cc = 0; cc < 4; ++cc)
    af[cc] = *(const bf16x8*)&hA[(mt * 4 + cc) * 512 + lane * 8];
  f32x16 acc[3];
#pragma unroll
  for (int m = 0; m < 3; ++m)
#pragma unroll
    for (int i = 0; i < 16; ++i) acc[m][i] = 0.f;
#pragma unroll
  for (int m = 0; m < 3; ++m)
#pragma unroll
    for (int cc = 0; cc < 4; ++cc)
      acc[m] = __builtin_amdgcn_mfma_f32_32x32x16_bf16(af[cc], wf[m][cc], acc[m], 0, 0, 0);

  const int o = 32 * nt + (lane & 31);
  const float bqv = bq[o], bkv = bk[o], bvv = bv[o];
  const float SQ = 0.18033688011112042f;  // 0.125 * log2(e)
  const size_t ktile = ((size_t)(b * 64 + blockIdx.x)) * 4096;
#pragma unroll
  for (int r = 0; r < 16; ++r) {
    const int tok = 32 * mt + (r & 3) + 8 * (r >> 2) + 4 * hi;
    const size_t gt = (size_t)(b * 4096 + t0 + tok);
    qo[gt * 64 + o] = f2b((acc[0][r] + bqv) * SQ);
    ko[ktile + ((tok >> 5) * 4 + (o >> 4)) * 512 +
       ((tok & 31) + 32 * ((o >> 3) & 1)) * 8 + (o & 7)] = f2b(acc[1][r] + bkv);
  }
  __syncthreads();
#pragma unroll
  for (int r = 0; r < 16; ++r) {
    const int tok = 32 * mt + (r & 3) + 8 * (r >> 2) + 4 * hi;
    hA[tok * 64 + o] = f2b(acc[2][r] + bvv);
  }
  __syncthreads();
#pragma unroll
  for (int half = 0; half < 2; ++half) {
    const int base = tid * 8 + half * 2048;
    const int sub = base >> 9, lp = (base >> 3) & 63;
    const int db = sub >> 2, ks = sub & 3;
    const int d = 32 * db + (lp & 31);
    const int k6b = 16 * ks + 8 * (lp >> 5);
    uint4 g;
    g.x = ((unsigned)hA[(k6b + 1) * 64 + d] << 16) | hA[(k6b + 0) * 64 + d];
    g.y = ((unsigned)hA[(k6b + 3) * 64 + d] << 16) | hA[(k6b + 2) * 64 + d];
    g.z = ((unsigned)hA[(k6b + 5) * 64 + d] << 16) | hA[(k6b + 4) * 64 + d];
    g.w = ((unsigned)hA[(k6b + 7) * 64 + d] << 16) | hA[(k6b + 6) * 64 + d];
    *(uint4*)&vo[ktile + base] = g;
  }
}

// ---------------- kernel 3: flash attention (v5 structure + VALU diet) ---
// grid (16 bs = b*2+sp, 32 qtile) x 512 threads.
__global__ __launch_bounds__(512, 2) void k_attn(
    const unsigned short* __restrict__ qg, const unsigned short* __restrict__ Kg,
    const unsigned short* __restrict__ Vg,
    float* __restrict__ lb, float* __restrict__ outp) {
  __shared__ unsigned short KV[2][2][8192];  // [half][buf][ K 4096 | V 4096 ]
  __shared__ float lred[4][64];
  const int bs = blockIdx.x, qt = blockIdx.y;
  const int b = bs >> 1, sp = bs & 1;
  const int tid = threadIdx.x, w = tid >> 6, lane = tid & 63;
  const int h = w >> 2, p = w & 3;
  const int q32 = lane & 31, hi = lane >> 5;
  const int qrow = qt * 128 + p * 32 + q32;
  const int tid4 = tid & 255;
  const int wq = p;

  bf16x8 qf[4];
  {
    const unsigned short* qsrc = qg + ((size_t)(b * 4096 + qrow)) * 64 + 8 * hi;
#pragma unroll
    for (int cc = 0; cc < 4; ++cc) qf[cc] = *(const bf16x8*)(qsrc + cc * 16);
  }

  // persistent zero accumulator seed: first MFMA of each tile uses this as C,
  // so the compiler never re-zeroes st0/st1 (saves 32 v_mov per tile).
  f32x16 zvec;
#pragma unroll
  for (int i = 0; i < 16; ++i) zvec[i] = 0.f;
  asm volatile("" : "+v"(zvec));  // keep it live/opaque

  f32x16 o[2];
#pragma unroll
  for (int i = 0; i < 16; ++i) { o[0][i] = 0.f; o[1][i] = 0.f; }
  float lrun = 0.f;

  const unsigned short* kgb = Kg + ((size_t)(b * 64 + sp * 32 + h * 16)) * 4096;
  const unsigned short* vgb = Vg + ((size_t)(b * 64 + sp * 32 + h * 16)) * 4096;

  auto STAGE = [&](int tt) {
    const int buf = tt & 1;
    const unsigned short* ks = kgb + (size_t)tt * 4096 + (size_t)tid4 * 8;
    const unsigned short* vs = vgb + (size_t)tt * 4096 + (size_t)tid4 * 8;
    GLL(ks, &KV[h][buf][wq * 512]);
    GLL(ks + 2048, &KV[h][buf][2048 + wq * 512]);
    GLL(vs, &KV[h][buf][4096 + wq * 512]);
    GLL(vs + 2048, &KV[h][buf][4096 + 2048 + wq * 512]);
  };

  STAGE(0);

  for (int t = 0; t < 16; ++t) {
    asm volatile("s_waitcnt vmcnt(0)" ::: "memory");
    __syncthreads();
    __builtin_amdgcn_sched_barrier(0);
    if (t < 15) STAGE(t + 1);

    const int buf = t & 1;
    const unsigned short* Kl = &KV[h][buf][0];
    const unsigned short* Vl = &KV[h][buf][4096];

    f32x16 st0, st1;
    __builtin_amdgcn_s_setprio(1);
    {
      const bf16x8 a0 = *(const bf16x8*)&Kl[0 * 512 + lane * 8];
      st0 = __builtin_amdgcn_mfma_f32_32x32x16_bf16(a0, qf[0], zvec, 0, 0, 0);
      const bf16x8 a1 = *(const bf16x8*)&Kl[4 * 512 + lane * 8];
      st1 = __builtin_amdgcn_mfma_f32_32x32x16_bf16(a1, qf[0], zvec, 0, 0, 0);
    }
#pragma unroll
    for (int cc = 1; cc < 4; ++cc) {
      const bf16x8 a0 = *(const bf16x8*)&Kl[(0 * 4 + cc) * 512 + lane * 8];
      st0 = __builtin_amdgcn_mfma_f32_32x32x16_bf16(a0, qf[cc], st0, 0, 0, 0);
      const bf16x8 a1 = *(const bf16x8*)&Kl[(1 * 4 + cc) * 512 + lane * 8];
      st1 = __builtin_amdgcn_mfma_f32_32x32x16_bf16(a1, qf[cc], st1, 0, 0, 0);
    }
    __builtin_amdgcn_s_setprio(0);

    // no-max softmax: P = exp2(s); element casts -> v_cvt_pk_bf16_f32;
    // 4-chain l accumulation.
    union PK { unsigned u[8]; __bf16 e[16]; } pk[2];
    {
      float l0 = 0.f, l1 = 0.f, l2 = 0.f, l3 = 0.f;
#pragma unroll
      for (int ks2 = 0; ks2 < 2; ++ks2) {
        const f32x16 s = ks2 ? st1 : st0;
#pragma unroll
        for (int i = 0; i < 16; i += 4) {
          const float e0 = __builtin_amdgcn_exp2f(s[i + 0]);
          const float e1 = __builtin_amdgcn_exp2f(s[i + 1]);
          const float e2 = __builtin_amdgcn_exp2f(s[i + 2]);
          const float e3 = __builtin_amdgcn_exp2f(s[i + 3]);
          l0 += e0; l1 += e1; l2 += e2; l3 += e3;
          pk[ks2].e[i + 0] = (__bf16)e0; pk[ks2].e[i + 1] = (__bf16)e1;
          pk[ks2].e[i + 2] = (__bf16)e2; pk[ks2].e[i + 3] = (__bf16)e3;
        }
      }
      lrun += (l0 + l1) + (l2 + l3);
    }

    __builtin_amdgcn_s_setprio(1);
#pragma unroll
    for (int t2 = 0; t2 < 2; ++t2)
#pragma unroll
      for (int s = 0; s < 2; ++s) {
        union { bf16x8 v; unsigned u[4]; } fr;
#if __has_builtin(__builtin_amdgcn_permlane32_swap)
        const u32x2 r02 = __builtin_amdgcn_permlane32_swap(
            pk[t2].u[4 * s + 0], pk[t2].u[4 * s + 2], false, false);
        const u32x2 r13 = __builtin_amdgcn_permlane32_swap(
            pk[t2].u[4 * s + 1], pk[t2].u[4 * s + 3], false, false);
        fr.u[0] = r02[0]; fr.u[1] = r13[0]; fr.u[2] = r02[1]; fr.u[3] = r13[1];
#else
        const unsigned u0 = __shfl_xor(hi ? pk[t2].u[4 * s + 0] : pk[t2].u[4 * s + 2], 32);
        const unsigned u1 = __shfl_xor(hi ? pk[t2].u[4 * s + 1] : pk[t2].u[4 * s + 3], 32);
        fr.u[0] = hi ? u0 : pk[t2].u[4 * s + 0];
        fr.u[1] = hi ? u1 : pk[t2].u[4 * s + 1];
        fr.u[2] = hi ? pk[t2].u[4 * s + 2] : u0;
        fr.u[3] = hi ? pk[t2].u[4 * s + 3] : u1;
#endif
        const int kc = t2 * 2 + s;
        const bf16x8 v0 = *(const bf16x8*)&Vl[(0 * 4 + kc) * 512 + lane * 8];
        o[0] = __builtin_amdgcn_mfma_f32_32x32x16_bf16(v0, fr.v, o[0], 0, 0, 0);
        const bf16x8 v1 = *(const bf16x8*)&Vl[(1 * 4 + kc) * 512 + lane * 8];
        o[1] = __builtin_amdgcn_mfma_f32_32x32x16_bf16(v1, fr.v, o[1], 0, 0, 0);
      }
    __builtin_amdgcn_s_setprio(0);
  }

  // in-block half combine: waves h=1 hand partials to h=0 via LDS (KV reuse).
  __syncthreads();
  float* cb = (float*)&KV[0][0][0];
  if (h == 1) {
#pragma unroll
    for (int db = 0; db < 2; ++db)
#pragma unroll
      for (int i = 0; i < 16; ++i)
        cb[p * 2048 + (db * 16 + i) * 64 + lane] = o[db][i];
    lred[p][lane] = lrun;
  }
  __syncthreads();
  if (h == 0) {
#pragma unroll
    for (int db = 0; db < 2; ++db)
#pragma unroll
      for (int i = 0; i < 16; ++i)
        o[db][i] += cb[p * 2048 + (db * 16 + i) * 64 + lane];
    lrun += lred[p][lane];
    lrun += __shfl_xor(lrun, 32);

    char* ob = (char*)outp + ((size_t)(b * 4096 + qrow)) * 256 + sp * 128;
#pragma unroll
    for (int db = 0; db < 2; ++db)
#pragma unroll
      for (int u = 0; u < 4; ++u) {
        ushort4 s;  // d = 32*db + 8*u + 4*hi + j
        s.x = f2b(o[db][4 * u + 0]); s.y = f2b(o[db][4 * u + 1]);
        s.z = f2b(o[db][4 * u + 2]); s.w = f2b(o[db][4 * u + 3]);
        *(ushort4*)(ob + (size_t)(32 * db + 8 * u + 4 * hi) * 2) = s;
      }
    if (hi == 0) lb[((size_t)(b * 2) + sp) * 4096 + qrow] = lrun;
  }
}

// ---------------- kernel 4: combine + Wp proj + bias + residual (MFMA) ---
__global__ __launch_bounds__(256) void k_comb(
    const unsigned short* __restrict__ wsW, const float* __restrict__ bp,
    const float* __restrict__ x, const float* __restrict__ lb,
    float* __restrict__ out) {
  __shared__ unsigned short hA[4096];
  const int b = blockIdx.y, tid = threadIdx.x, t0 = blockIdx.x * 64;
  const int w = tid >> 6, lane = tid & 63;
  const int mt = w >> 1, nt = w & 1, hi = lane >> 5;

  bf16x8 wf[4];
#pragma unroll
  for (int cc = 0; cc < 4; ++cc)
    wf[cc] = *(const bf16x8*)&wsW[3 * 4096 + (nt * 4 + cc) * 512 + lane * 8];

#pragma unroll
  for (int it = 0; it < 4; ++it) {
    const int idx = tid * 4 + it * 1024;
    const int tl = idx >> 6, d0 = idx & 63;
    const int trow = t0 + tl;
    const size_t gt = (size_t)(b * 4096 + trow);
    const float lsum = lb[((size_t)b * 2 + 0) * 4096 + trow] +
                       lb[((size_t)b * 2 + 1) * 4096 + trow];
    const float invL = 1.0f / lsum;
    const char* pb = (const char*)out + gt * 256;
    const ushort4 p0 = *(const ushort4*)(pb + (size_t)d0 * 2);
    const ushort4 p1 = *(const ushort4*)(pb + 128 + (size_t)d0 * 2);
    ushort4 hv;
    hv.x = f2b((b2f(p0.x) + b2f(p1.x)) * invL);
    hv.y = f2b((b2f(p0.y) + b2f(p1.y)) * invL);
    hv.z = f2b((b2f(p0.z) + b2f(p1.z)) * invL);
    hv.w = f2b((b2f(p0.w) + b2f(p1.w)) * invL);
    *(ushort4*)&hA[a_off(tl, d0)] = hv;
  }
  __syncthreads();

  f32x16 acc2;
#pragma unroll
  for (int i = 0; i < 16; ++i) acc2[i] = 0.f;
#pragma unroll
  for (int cc = 0; cc < 4; ++cc) {
    const bf16x8 a = *(const bf16x8*)&hA[(mt * 4 + cc) * 512 + lane * 8];
    acc2 = __builtin_amdgcn_mfma_f32_32x32x16_bf16(a, wf[cc], acc2, 0, 0, 0);
  }
  const int o = 32 * nt + (lane & 31);
  const float bpv = bp[o];
#pragma unroll
  for (int r = 0; r < 16; ++r) {
    const int tok = 32 * mt + (r & 3) + 8 * (r >> 2) + 4 * hi;
    const size_t gt = (size_t)(b * 4096 + t0 + tok);
    out[gt * 64 + o] = acc2[r] + bpv + x[gt * 64 + o];
  }
}

// ---------------- launch --------------------------------------------------
extern "C" void kernel_launch(void* const* d_in, const int* in_sizes, int n_in,
                              void* d_out, int out_size, void* d_ws,
                              size_t ws_size, hipStream_t stream) {
  const float* x     = (const float*)d_in[0];
  const float* gamma = (const float*)d_in[1];
  const float* beta  = (const float*)d_in[2];
  const float* Wq    = (const float*)d_in[3];
  const float* bq    = (const float*)d_in[4];
  const float* Wk    = (const float*)d_in[5];
  const float* bk    = (const float*)d_in[6];
  const float* Wv    = (const float*)d_in[7];
  const float* bv    = (const float*)d_in[8];
  const float* Wp    = (const float*)d_in[9];
  const float* bp    = (const float*)d_in[10];
  float* out = (float*)d_out;

  char* ws = (char*)d_ws;
  float* part = (float*)ws;               // 64 KB (dead after k_gnqkv)
  float* lbuf = (float*)ws;               // 256 KB (time-shared with part)
  unsigned short* wsW = (unsigned short*)(ws + 262144);  // 32 KB bf16 frag weights
  unsigned short* qb = (unsigned short*)(ws + 524288);   // 4 MB
  unsigned short* kb = qb + (size_t)8 * 4096 * 64;       // 4 MB (frag-order)
  unsigned short* vb = kb + (size_t)8 * 4096 * 64;       // 4 MB (frag-order)

  k_part<<<dim3(32, 8), 256, 0, stream>>>(x, Wq, Wk, Wv, Wp, part, wsW);
  k_gnqkv<<<dim3(64, 8), 256, 0, stream>>>(x, gamma, beta, bq, bk, bv,
                                           part, wsW, qb, kb, vb);
  k_attn<<<dim3(16, 32), 512, 0, stream>>>(qb, kb, vb, lbuf, out);
  k_comb<<<dim3(64, 8), 256, 0, stream>>>(wsW, bp, x, lbuf, out);
}

// Round 12
// 66.650 us; speedup vs baseline: 1.1142x; 1.1142x over previous
//
#include <hip/hip_runtime.h>

// attn_block: GroupNorm(32) -> QKV 1x1 -> full spatial self-attention -> proj -> residual
// B=8, H=W=64 (N=4096 tokens), C=D=64, single head, scale=1/8 (folded into q with log2e).
//
// v12 == v10 (measured best, 66.7 us): v5 k_attn structure (8 waves, in-block half
// combine, one barrier+drain per tile), bs-major grid for L2 locality, weights
// pre-converted to bf16 frag-order in k_part, reg-direct weight fragments.

typedef __bf16 bf16x8 __attribute__((ext_vector_type(8)));
typedef float f32x16 __attribute__((ext_vector_type(16)));
typedef unsigned u32x2 __attribute__((ext_vector_type(2)));

static __device__ __forceinline__ unsigned short f2b(float f) {
  union { __bf16 b; unsigned short u; } c; c.b = (__bf16)f; return c.u;
}
static __device__ __forceinline__ float b2f(unsigned short u) {
  union { float f; unsigned u; } c; c.u = ((unsigned)u) << 16; return c.f;
}
static __device__ __forceinline__ unsigned pack2(float lo, float hi_) {
  return ((unsigned)f2b(hi_) << 16) | (unsigned)f2b(lo);
}
// A/B-frag (mfma_32x32x16, K-contiguous-8) element offset inside a 64x64 tile.
static __device__ __forceinline__ int a_off(int t, int c) {
  return ((t >> 5) * 4 + (c >> 4)) * 512 + ((t & 31) + 32 * ((c >> 3) & 1)) * 8 + (c & 7);
}
static __device__ __forceinline__ int b_off(int o, int d) {
  return ((o >> 5) * 4 + (d >> 4)) * 512 + ((o & 31) + 32 * ((d >> 3) & 1)) * 8 + (d & 7);
}

#define GLL(src, dst) __builtin_amdgcn_global_load_lds(                        \
    (const __attribute__((address_space(1))) void*)(src),                     \
    (__attribute__((address_space(3))) void*)(dst), 16, 0, 0)

// ---------------- kernel 1: GN partial sums + weight frag conversion -----
__global__ __launch_bounds__(256) void k_part(
    const float* __restrict__ x,
    const float* __restrict__ Wq, const float* __restrict__ Wk,
    const float* __restrict__ Wv, const float* __restrict__ Wp,
    float* __restrict__ part, unsigned short* __restrict__ wsW) {
  const int b = blockIdx.y, ch = blockIdx.x, tid = threadIdx.x;

  if (b == 0) {  // weight conversion: 16384 elems over 32 blocks x 256 thr x 2
    const float* Wsrc[4] = {Wq, Wk, Wv, Wp};
    const int e0 = ch * 512 + tid * 2;
#pragma unroll
    for (int j = 0; j < 2; ++j) {
      const int e = e0 + j, m = e >> 12, idx = e & 4095;
      const int d = idx >> 6, o = idx & 63;
      wsW[m * 4096 + b_off(o, d)] = f2b(Wsrc[m][idx]);
    }
  }

  const size_t base = ((size_t)(b * 4096 + ch * 128)) * 64;
  float s0 = 0.f, q0 = 0.f, s1 = 0.f, q1 = 0.f;
#pragma unroll
  for (int it = 0; it < 8; ++it) {
    const float4 v = *(const float4*)&x[base + (size_t)tid * 4 + (size_t)it * 1024];
    s0 += v.x + v.y; q0 += v.x * v.x + v.y * v.y;
    s1 += v.z + v.w; q1 += v.z * v.z + v.w * v.w;
  }
  for (int m = 16; m < 64; m <<= 1) {
    s0 += __shfl_xor(s0, m); q0 += __shfl_xor(q0, m);
    s1 += __shfl_xor(s1, m); q1 += __shfl_xor(q1, m);
  }
  __shared__ float red[4][16][4];
  const int lane = tid & 63, wv = tid >> 6;
  if (lane < 16) {
    red[wv][lane][0] = s0; red[wv][lane][1] = q0;
    red[wv][lane][2] = s1; red[wv][lane][3] = q1;
  }
  __syncthreads();
  if (tid < 64) {
    const int ci = tid >> 2, sel = tid & 3;
    const float v = red[0][ci][sel] + red[1][ci][sel] +
                    red[2][ci][sel] + red[3][ci][sel];
    const int g = ci * 2 + (sel >> 1);
    part[(((size_t)b * 32 + g) * 32 + ch) * 2 + (sel & 1)] = v;
  }
}

// ---------------- kernel 2: GN stats finalize + GN + QKV proj (MFMA) -----
__global__ __launch_bounds__(256) void k_gnqkv(
    const float* __restrict__ x, const float* __restrict__ gamma,
    const float* __restrict__ beta,
    const float* __restrict__ bq, const float* __restrict__ bk,
    const float* __restrict__ bv,
    const float* __restrict__ part, const unsigned short* __restrict__ wsW,
    unsigned short* __restrict__ qo, unsigned short* __restrict__ ko,
    unsigned short* __restrict__ vo) {
  __shared__ unsigned short hA[4096];  // A-frags of h; reused as V bounce
  __shared__ float2 stl[32];
  const int b = blockIdx.y, tid = threadIdx.x, t0 = blockIdx.x * 64;
  const int w = tid >> 6, lane = tid & 63;
  const int mt = w >> 1, nt = w & 1, hi = lane >> 5;

  // weight B-frags straight from global (L2-hot), issued early
  bf16x8 wf[3][4];
#pragma unroll
  for (int m = 0; m < 3; ++m)
#pragma unroll
    for (int cc = 0; cc < 4; ++cc)
      wf[m][cc] = *(const bf16x8*)&wsW[m * 4096 + (nt * 4 + cc) * 512 + lane * 8];

  if (tid < 32) {
    const float* p = part + ((size_t)(b * 32 + tid)) * 64;
    float s = 0.f, q = 0.f;
#pragma unroll
    for (int c4 = 0; c4 < 16; ++c4) {
      const float4 v = *(const float4*)&p[c4 * 4];
      s += v.x + v.z; q += v.y + v.w;
    }
    const float mean = s * (1.0f / 8192.0f);
    const float var = fmaxf(q * (1.0f / 8192.0f) - mean * mean, 0.0f);
    stl[tid] = make_float2(mean, rsqrtf(var + 1e-6f));
  }
  __syncthreads();

#pragma unroll
  for (int it = 0; it < 4; ++it) {
    const int idx = tid * 4 + it * 1024;
    const int tl = idx >> 6, c0 = idx & 63;
    const float4 xv = *(const float4*)&x[((size_t)(b * 4096 + t0 + tl)) * 64 + c0];
    const float2 s0 = stl[(c0 >> 1)];
    const float2 s1 = stl[(c0 >> 1) + 1];
    const float4 gm = *(const float4*)&gamma[c0];
    const float4 bt = *(const float4*)&beta[c0];
    ushort4 hv;
    hv.x = f2b((xv.x - s0.x) * s0.y * gm.x + bt.x);
    hv.y = f2b((xv.y - s0.x) * s0.y * gm.y + bt.y);
    hv.z = f2b((xv.z - s1.x) * s1.y * gm.z + bt.z);
    hv.w = f2b((xv.w - s1.x) * s1.y * gm.w + bt.w);
    *(ushort4*)&hA[a_off(tl, c0)] = hv;
  }
  __syncthreads();

  bf16x8 af[4];
#pragma unroll
  for (int cc = 0; cc < 4; ++cc)
    af[cc] = *(const bf16x8*)&hA[(mt * 4 + cc) * 512 + lane * 8];
  f32x16 acc[3];
#pragma unroll
  for (int m = 0; m < 3; ++m)
#pragma unroll
    for (int i = 0; i < 16; ++i) acc[m][i] = 0.f;
#pragma unroll
  for (int m = 0; m < 3; ++m)
#pragma unroll
    for (int cc = 0; cc < 4; ++cc)
      acc[m] = __builtin_amdgcn_mfma_f32_32x32x16_bf16(af[cc], wf[m][cc], acc[m], 0, 0, 0);

  const int o = 32 * nt + (lane & 31);
  const float bqv = bq[o], bkv = bk[o], bvv = bv[o];
  const float SQ = 0.18033688011112042f;  // 0.125 * log2(e)
  const size_t ktile = ((size_t)(b * 64 + blockIdx.x)) * 4096;
#pragma unroll
  for (int r = 0; r < 16; ++r) {
    const int tok = 32 * mt + (r & 3) + 8 * (r >> 2) + 4 * hi;
    const size_t gt = (size_t)(b * 4096 + t0 + tok);
    qo[gt * 64 + o] = f2b((acc[0][r] + bqv) * SQ);
    ko[ktile + ((tok >> 5) * 4 + (o >> 4)) * 512 +
       ((tok & 31) + 32 * ((o >> 3) & 1)) * 8 + (o & 7)] = f2b(acc[1][r] + bkv);
  }
  // V: bounce through LDS (C-layout), then coalesced frag-order store.
  __syncthreads();
#pragma unroll
  for (int r = 0; r < 16; ++r) {
    const int tok = 32 * mt + (r & 3) + 8 * (r >> 2) + 4 * hi;
    hA[tok * 64 + o] = f2b(acc[2][r] + bvv);
  }
  __syncthreads();
#pragma unroll
  for (int half = 0; half < 2; ++half) {
    const int base = tid * 8 + half * 2048;
    const int sub = base >> 9, lp = (base >> 3) & 63;
    const int db = sub >> 2, ks = sub & 3;
    const int d = 32 * db + (lp & 31);
    const int k6b = 16 * ks + 8 * (lp >> 5);
    uint4 g;
    g.x = ((unsigned)hA[(k6b + 1) * 64 + d] << 16) | hA[(k6b + 0) * 64 + d];
    g.y = ((unsigned)hA[(k6b + 3) * 64 + d] << 16) | hA[(k6b + 2) * 64 + d];
    g.z = ((unsigned)hA[(k6b + 5) * 64 + d] << 16) | hA[(k6b + 4) * 64 + d];
    g.w = ((unsigned)hA[(k6b + 7) * 64 + d] << 16) | hA[(k6b + 6) * 64 + d];
    *(uint4*)&vo[ktile + base] = g;
  }
}

// ---------------- kernel 3: flash attention (v5 structure, bs-major grid) ----
// grid (16 bs = b*2+sp, 32 qtile) x 512 threads.
// Wave w (0..7): key-half h = w>>2, q-wave p = w&3. Waves p and p+4 share q rows;
// partial O/l combined in-block through LDS. No-max softmax (exp2 domain).
__global__ __launch_bounds__(512, 2) void k_attn(
    const unsigned short* __restrict__ qg, const unsigned short* __restrict__ Kg,
    const unsigned short* __restrict__ Vg,
    float* __restrict__ lb, float* __restrict__ outp) {
  __shared__ unsigned short KV[2][2][8192];  // [half][buf][ K 4096 | V 4096 ]
  __shared__ float lred[4][64];
  const int bs = blockIdx.x, qt = blockIdx.y;
  const int b = bs >> 1, sp = bs & 1;
  const int tid = threadIdx.x, w = tid >> 6, lane = tid & 63;
  const int h = w >> 2, p = w & 3;
  const int q32 = lane & 31, hi = lane >> 5;
  const int qrow = qt * 128 + p * 32 + q32;
  const int tid4 = tid & 255;  // thread index within half-group
  const int wq = p;            // staging quarter within half

  bf16x8 qf[4];
  {
    const unsigned short* qsrc = qg + ((size_t)(b * 4096 + qrow)) * 64 + 8 * hi;
#pragma unroll
    for (int cc = 0; cc < 4; ++cc) qf[cc] = *(const bf16x8*)(qsrc + cc * 16);
  }

  f32x16 o[2];
#pragma unroll
  for (int i = 0; i < 16; ++i) { o[0][i] = 0.f; o[1][i] = 0.f; }
  float lrun = 0.f;

  const unsigned short* kgb = Kg + ((size_t)(b * 64 + sp * 32 + h * 16)) * 4096;
  const unsigned short* vgb = Vg + ((size_t)(b * 64 + sp * 32 + h * 16)) * 4096;

  auto STAGE = [&](int tt) {
    const int buf = tt & 1;
    const unsigned short* ks = kgb + (size_t)tt * 4096 + (size_t)tid4 * 8;
    const unsigned short* vs = vgb + (size_t)tt * 4096 + (size_t)tid4 * 8;
    GLL(ks, &KV[h][buf][wq * 512]);
    GLL(ks + 2048, &KV[h][buf][2048 + wq * 512]);
    GLL(vs, &KV[h][buf][4096 + wq * 512]);
    GLL(vs + 2048, &KV[h][buf][4096 + 2048 + wq * 512]);
  };

  STAGE(0);

  for (int t = 0; t < 16; ++t) {
    asm volatile("s_waitcnt vmcnt(0)" ::: "memory");
    __syncthreads();
    __builtin_amdgcn_sched_barrier(0);
    if (t < 15) STAGE(t + 1);

    const int buf = t & 1;
    const unsigned short* Kl = &KV[h][buf][0];
    const unsigned short* Vl = &KV[h][buf][4096];

    f32x16 st0, st1;
#pragma unroll
    for (int i = 0; i < 16; ++i) { st0[i] = 0.f; st1[i] = 0.f; }
    __builtin_amdgcn_s_setprio(1);
#pragma unroll
    for (int cc = 0; cc < 4; ++cc) {
      const bf16x8 a0 = *(const bf16x8*)&Kl[(0 * 4 + cc) * 512 + lane * 8];
      st0 = __builtin_amdgcn_mfma_f32_32x32x16_bf16(a0, qf[cc], st0, 0, 0, 0);
      const bf16x8 a1 = *(const bf16x8*)&Kl[(1 * 4 + cc) * 512 + lane * 8];
      st1 = __builtin_amdgcn_mfma_f32_32x32x16_bf16(a1, qf[cc], st1, 0, 0, 0);
    }
    __builtin_amdgcn_s_setprio(0);

    // no-max softmax: P = exp2(s); per-lane partial l only.
    float rs0 = 0.f, rs1 = 0.f;
#pragma unroll
    for (int r = 0; r < 16; ++r) {
      st0[r] = __builtin_amdgcn_exp2f(st0[r]); rs0 += st0[r];
      st1[r] = __builtin_amdgcn_exp2f(st1[r]); rs1 += st1[r];
    }
    lrun += rs0 + rs1;

    __builtin_amdgcn_s_setprio(1);
#pragma unroll
    for (int t2 = 0; t2 < 2; ++t2) {
      unsigned pk[8];
#pragma unroll
      for (int i = 0; i < 8; ++i)
        pk[i] = t2 ? pack2(st1[2 * i], st1[2 * i + 1])
                   : pack2(st0[2 * i], st0[2 * i + 1]);
#pragma unroll
      for (int s = 0; s < 2; ++s) {
        union { bf16x8 v; unsigned u[4]; } fr;
#if __has_builtin(__builtin_amdgcn_permlane32_swap)
        const u32x2 r02 = __builtin_amdgcn_permlane32_swap(pk[4 * s + 0], pk[4 * s + 2], false, false);
        const u32x2 r13 = __builtin_amdgcn_permlane32_swap(pk[4 * s + 1], pk[4 * s + 3], false, false);
        fr.u[0] = r02[0]; fr.u[1] = r13[0]; fr.u[2] = r02[1]; fr.u[3] = r13[1];
#else
        const unsigned u0 = __shfl_xor(hi ? pk[4 * s + 0] : pk[4 * s + 2], 32);
        const unsigned u1 = __shfl_xor(hi ? pk[4 * s + 1] : pk[4 * s + 3], 32);
        fr.u[0] = hi ? u0 : pk[4 * s + 0];
        fr.u[1] = hi ? u1 : pk[4 * s + 1];
        fr.u[2] = hi ? pk[4 * s + 2] : u0;
        fr.u[3] = hi ? pk[4 * s + 3] : u1;
#endif
        const int kc = t2 * 2 + s;
        const bf16x8 v0 = *(const bf16x8*)&Vl[(0 * 4 + kc) * 512 + lane * 8];
        o[0] = __builtin_amdgcn_mfma_f32_32x32x16_bf16(v0, fr.v, o[0], 0, 0, 0);
        const bf16x8 v1 = *(const bf16x8*)&Vl[(1 * 4 + kc) * 512 + lane * 8];
        o[1] = __builtin_amdgcn_mfma_f32_32x32x16_bf16(v1, fr.v, o[1], 0, 0, 0);
      }
    }
    __builtin_amdgcn_s_setprio(0);
  }

  // in-block half combine: waves h=1 hand partials to h=0 via LDS (KV reuse).
  __syncthreads();  // all waves done reading KV -> safe to reuse as f32 buffer
  float* cb = (float*)&KV[0][0][0];  // 4 pairs x 2048 floats = 32 KB
  if (h == 1) {
#pragma unroll
    for (int db = 0; db < 2; ++db)
#pragma unroll
      for (int i = 0; i < 16; ++i)
        cb[p * 2048 + (db * 16 + i) * 64 + lane] = o[db][i];
    lred[p][lane] = lrun;
  }
  __syncthreads();
  if (h == 0) {
#pragma unroll
    for (int db = 0; db < 2; ++db)
#pragma unroll
      for (int i = 0; i < 16; ++i)
        o[db][i] += cb[p * 2048 + (db * 16 + i) * 64 + lane];
    lrun += lred[p][lane];
    lrun += __shfl_xor(lrun, 32);

    char* ob = (char*)outp + ((size_t)(b * 4096 + qrow)) * 256 + sp * 128;
#pragma unroll
    for (int db = 0; db < 2; ++db)
#pragma unroll
      for (int u = 0; u < 4; ++u) {
        ushort4 s;  // d = 32*db + 8*u + 4*hi + j
        s.x = f2b(o[db][4 * u + 0]); s.y = f2b(o[db][4 * u + 1]);
        s.z = f2b(o[db][4 * u + 2]); s.w = f2b(o[db][4 * u + 3]);
        *(ushort4*)(ob + (size_t)(32 * db + 8 * u + 4 * hi) * 2) = s;
      }
    if (hi == 0) lb[((size_t)(b * 2) + sp) * 4096 + qrow] = lrun;
  }
}

// ---------------- kernel 4: combine + Wp proj + bias + residual (MFMA) ---
__global__ __launch_bounds__(256) void k_comb(
    const unsigned short* __restrict__ wsW, const float* __restrict__ bp,
    const float* __restrict__ x, const float* __restrict__ lb,
    float* __restrict__ out) {
  __shared__ unsigned short hA[4096];
  const int b = blockIdx.y, tid = threadIdx.x, t0 = blockIdx.x * 64;
  const int w = tid >> 6, lane = tid & 63;
  const int mt = w >> 1, nt = w & 1, hi = lane >> 5;

  bf16x8 wf[4];
#pragma unroll
  for (int cc = 0; cc < 4; ++cc)
    wf[cc] = *(const bf16x8*)&wsW[3 * 4096 + (nt * 4 + cc) * 512 + lane * 8];

#pragma unroll
  for (int it = 0; it < 4; ++it) {
    const int idx = tid * 4 + it * 1024;
    const int tl = idx >> 6, d0 = idx & 63;
    const int trow = t0 + tl;
    const size_t gt = (size_t)(b * 4096 + trow);
    const float lsum = lb[((size_t)b * 2 + 0) * 4096 + trow] +
                       lb[((size_t)b * 2 + 1) * 4096 + trow];
    const float invL = 1.0f / lsum;
    const char* pb = (const char*)out + gt * 256;
    const ushort4 p0 = *(const ushort4*)(pb + (size_t)d0 * 2);
    const ushort4 p1 = *(const ushort4*)(pb + 128 + (size_t)d0 * 2);
    ushort4 hv;
    hv.x = f2b((b2f(p0.x) + b2f(p1.x)) * invL);
    hv.y = f2b((b2f(p0.y) + b2f(p1.y)) * invL);
    hv.z = f2b((b2f(p0.z) + b2f(p1.z)) * invL);
    hv.w = f2b((b2f(p0.w) + b2f(p1.w)) * invL);
    *(ushort4*)&hA[a_off(tl, d0)] = hv;
  }
  __syncthreads();

  f32x16 acc2;
#pragma unroll
  for (int i = 0; i < 16; ++i) acc2[i] = 0.f;
#pragma unroll
  for (int cc = 0; cc < 4; ++cc) {
    const bf16x8 a = *(const bf16x8*)&hA[(mt * 4 + cc) * 512 + lane * 8];
    acc2 = __builtin_amdgcn_mfma_f32_32x32x16_bf16(a, wf[cc], acc2, 0, 0, 0);
  }
  const int o = 32 * nt + (lane & 31);
  const float bpv = bp[o];
#pragma unroll
  for (int r = 0; r < 16; ++r) {
    const int tok = 32 * mt + (r & 3) + 8 * (r >> 2) + 4 * hi;
    const size_t gt = (size_t)(b * 4096 + t0 + tok);
    out[gt * 64 + o] = acc2[r] + bpv + x[gt * 64 + o];
  }
}

// ---------------- launch --------------------------------------------------
extern "C" void kernel_launch(void* const* d_in, const int* in_sizes, int n_in,
                              void* d_out, int out_size, void* d_ws,
                              size_t ws_size, hipStream_t stream) {
  const float* x     = (const float*)d_in[0];
  const float* gamma = (const float*)d_in[1];
  const float* beta  = (const float*)d_in[2];
  const float* Wq    = (const float*)d_in[3];
  const float* bq    = (const float*)d_in[4];
  const float* Wk    = (const float*)d_in[5];
  const float* bk    = (const float*)d_in[6];
  const float* Wv    = (const float*)d_in[7];
  const float* bv    = (const float*)d_in[8];
  const float* Wp    = (const float*)d_in[9];
  const float* bp    = (const float*)d_in[10];
  float* out = (float*)d_out;

  char* ws = (char*)d_ws;
  float* part = (float*)ws;               // 64 KB (dead after k_gnqkv)
  float* lbuf = (float*)ws;               // 256 KB (time-shared with part)
  unsigned short* wsW = (unsigned short*)(ws + 262144);  // 32 KB bf16 frag weights
  unsigned short* qb = (unsigned short*)(ws + 524288);   // 4 MB
  unsigned short* kb = qb + (size_t)8 * 4096 * 64;       // 4 MB (frag-order)
  unsigned short* vb = kb + (size_t)8 * 4096 * 64;       // 4 MB (frag-order)

  k_part<<<dim3(32, 8), 256, 0, stream>>>(x, Wq, Wk, Wv, Wp, part, wsW);
  k_gnqkv<<<dim3(64, 8), 256, 0, stream>>>(x, gamma, beta, bq, bk, bv,
                                           part, wsW, qb, kb, vb);
  k_attn<<<dim3(16, 32), 512, 0, stream>>>(qb, kb, vb, lbuf, out);
  k_comb<<<dim3(64, 8), 256, 0, stream>>>(wsW, bp, x, lbuf, out);
}